// Round 1
// baseline (278.001 us; speedup 1.0000x reference)
//
#include <hip/hip_runtime.h>

#define HW 4096
#define CC 64
#define KK 8
#define NB 4

// workspace layout in floats
#define OFF_F  0
#define OFF_G  (NB*HW*KK)            // 131072
#define OFF_H  (2*NB*HW*KK)          // 262144
#define OFF_ZP (OFF_H + NB*HW*CC)    // 1310720
#define OFF_O  (OFF_ZP + 8*NB*HW)    // 1441792
// total floats = 2490368 (~9.96 MB)

// ---------------------------------------------------------------------------
// Kernel 1: f = Wf@x + bf, g = Wg@x + bg, h = Wh@x + bh  (per-pixel 1x1 conv)
// f,g stored [b][n][8]; h stored [b][n][64]. Block = 256 thr, one 64-pixel
// tile per block; each wave owns 20 of the 80 output rows (8 f + 8 g + 64 h).
// Weights are read straight from global (wave-uniform rows -> L1 broadcast).
// ---------------------------------------------------------------------------
__global__ __launch_bounds__(256) void k_prep(
    const float* __restrict__ x,
    const float* __restrict__ Wf, const float* __restrict__ bf,
    const float* __restrict__ Wg, const float* __restrict__ bg,
    const float* __restrict__ Wh, const float* __restrict__ bh,
    float* __restrict__ f, float* __restrict__ g, float* __restrict__ h)
{
    const int nt = blockIdx.x, b = blockIdx.y;
    const int tid = (int)threadIdx.x;
    const int w = tid >> 6, nl = tid & 63;
    const int n = nt * 64 + nl;
    const int r0 = w * 20;

    float acc[20];
    const float* wrow[20];
#pragma unroll
    for (int rr = 0; rr < 20; ++rr) {
        int r = r0 + rr;
        if (r < 8)       { wrow[rr] = Wf + r * 64;        acc[rr] = bf[r]; }
        else if (r < 16) { wrow[rr] = Wg + (r - 8) * 64;  acc[rr] = bg[r - 8]; }
        else             { wrow[rr] = Wh + (r - 16) * 64; acc[rr] = bh[r - 16]; }
    }

    const float* xb = x + (size_t)b * CC * HW + n;
    for (int c0 = 0; c0 < 64; c0 += 4) {
        float x0 = xb[(c0 + 0) * HW];
        float x1 = xb[(c0 + 1) * HW];
        float x2 = xb[(c0 + 2) * HW];
        float x3 = xb[(c0 + 3) * HW];
#pragma unroll
        for (int rr = 0; rr < 20; ++rr) {
            const float4 wv = *(const float4*)(wrow[rr] + c0);
            acc[rr] += wv.x * x0 + wv.y * x1 + wv.z * x2 + wv.w * x3;
        }
    }

    const size_t bn = (size_t)b * HW + n;
#pragma unroll
    for (int rr = 0; rr < 20; ++rr) {
        int r = r0 + rr;
        if (r < 8)       f[bn * 8 + r] = acc[rr];
        else if (r < 16) g[bn * 8 + (r - 8)] = acc[rr];
        else             h[bn * 64 + (r - 16)] = acc[rr];
    }
}

// ---------------------------------------------------------------------------
// Kernel 2: Z partials. Z_n = sum_i exp(f_i . g_n).  Grid (16 ntile, 8 ichunk,
// 4 b); thread owns one n (g row in regs), loops over a 512-wide i chunk.
// f rows are block-uniform -> compiler emits scalar loads.
// ---------------------------------------------------------------------------
__global__ __launch_bounds__(256) void k_zpart(
    const float* __restrict__ f, const float* __restrict__ g,
    float* __restrict__ zp)
{
    const int nt = blockIdx.x, ich = blockIdx.y, b = blockIdx.z;
    const int n = nt * 256 + (int)threadIdx.x;
    const float* gp = g + ((size_t)b * HW + n) * 8;
    const float4 g0 = *(const float4*)(gp);
    const float4 g1 = *(const float4*)(gp + 4);
    const float* fb = f + (size_t)b * HW * 8 + (size_t)ich * 512 * 8;
    float z = 0.f;
#pragma unroll 4
    for (int i = 0; i < 512; ++i) {
        const float* fr = fb + i * 8;
        float s = fr[0] * g0.x + fr[1] * g0.y + fr[2] * g0.z + fr[3] * g0.w
                + fr[4] * g1.x + fr[5] * g1.y + fr[6] * g1.z + fr[7] * g1.w;
        z += __expf(s);
    }
    zp[((size_t)ich * NB + b) * HW + n] = z;
}

// ---------------------------------------------------------------------------
// Kernel 2c: h[b][n][:] *= 1 / (sum of 8 Z partials)
// ---------------------------------------------------------------------------
__global__ __launch_bounds__(256) void k_scale(
    const float* __restrict__ zp, float* __restrict__ h)
{
    const int t = blockIdx.x * 256 + (int)threadIdx.x;  // 16384 total
    const int b = t >> 12, n = t & 4095;
    float z = 0.f;
#pragma unroll
    for (int ic = 0; ic < 8; ++ic) z += zp[((size_t)ic * NB + b) * HW + n];
    const float w = 1.0f / z;
    float4* hp = (float4*)(h + ((size_t)b * HW + n) * 64);
#pragma unroll
    for (int q = 0; q < 16; ++q) {
        float4 v = hp[q];
        v.x *= w; v.y *= w; v.z *= w; v.w *= w;
        hp[q] = v;
    }
}

// ---------------------------------------------------------------------------
// Kernel 3: o[b][c][m] += sum_{n>=m} exp(f_m.g_n) * h'[c][n]
// Block = 256 thr computing a 64m x 64c tile, looping over 64-wide n chunks.
// Per chunk: stage g/h' tiles, compute P tile (64n x 64m, padded 68) in LDS,
// then register-tiled 4m x 4c FMA GEMM. Load balance: blockIdx.z r in [0,64)
// maps to m-tile via fold (r<32 ? r : 95-r) so blocks r and r+32 pair tiles
// mt and 63-mt; even/odd n-chunks split across blockIdx.x; partial sums are
// atomicAdd'ed into o (zeroed by memset).
// ---------------------------------------------------------------------------
__global__ __launch_bounds__(256) void k_attn(
    const float* __restrict__ f, const float* __restrict__ g,
    const float* __restrict__ h, float* __restrict__ o)
{
    __shared__ float fT[64 * 8];
    __shared__ float gT[64 * 8];
    __shared__ float hT[64 * 64];
    __shared__ float pT[64 * 68];   // [nn][mm], padded to 68 to break conflicts

    const int hx = blockIdx.x;               // 0/1: even/odd chunks
    const int b  = blockIdx.y;
    const int r  = blockIdx.z;
    const int mt = (r < 32) ? r : 95 - r;    // folded m-tile index
    const int m0 = mt * 64;
    const int tid = (int)threadIdx.x;
    const int tm = tid & 15, tc = tid >> 4;

    const float* fsrc = f + ((size_t)b * HW + m0) * 8;
    for (int idx = tid; idx < 512; idx += 256) fT[idx] = fsrc[idx];

    float4 acc[4];
#pragma unroll
    for (int i = 0; i < 4; ++i) acc[i] = make_float4(0.f, 0.f, 0.f, 0.f);

    for (int nc = mt + hx; nc < 64; nc += 2) {
        const int n0 = nc * 64;
        const float* gsrc = g + ((size_t)b * HW + n0) * 8;
        for (int idx = tid; idx < 512; idx += 256) gT[idx] = gsrc[idx];
        const float* hsrc = h + ((size_t)b * HW + n0) * 64;
#pragma unroll
        for (int q = 0; q < 4; ++q) {
            int idx = q * 256 + tid;
            ((float4*)hT)[idx] = ((const float4*)hsrc)[idx];
        }
        __syncthreads();

        // ---- Phase A: P tile ----
        {
            const int nn = tid >> 2;
            const int mmB = (tid & 3) * 16;
            const float4 ga = *(const float4*)&gT[nn * 8];
            const float4 gb = *(const float4*)&gT[nn * 8 + 4];
            const bool diag = (nc == mt);
#pragma unroll
            for (int mq = 0; mq < 4; ++mq) {
                float4 pv;
#pragma unroll
                for (int j = 0; j < 4; ++j) {
                    const int mm = mmB + mq * 4 + j;
                    const float4 fa = *(const float4*)&fT[mm * 8];
                    const float4 fb2 = *(const float4*)&fT[mm * 8 + 4];
                    float s = fa.x * ga.x + fa.y * ga.y + fa.z * ga.z + fa.w * ga.w
                            + fb2.x * gb.x + fb2.y * gb.y + fb2.z * gb.z + fb2.w * gb.w;
                    float p = __expf(s);
                    if (diag && nn < mm) p = 0.f;
                    ((float*)&pv)[j] = p;
                }
                *(float4*)&pT[nn * 68 + mmB + mq * 4] = pv;
            }
        }
        __syncthreads();

        // ---- Phase B: acc[4m][4c] += P[nn][tm4] x h'[nn][tc4] ----
#pragma unroll 8
        for (int nn = 0; nn < 64; ++nn) {
            const float4 pa = *(const float4*)&pT[nn * 68 + tm * 4];
            const float4 hb = *(const float4*)&hT[nn * 64 + tc * 4];
            acc[0].x += pa.x * hb.x; acc[0].y += pa.x * hb.y; acc[0].z += pa.x * hb.z; acc[0].w += pa.x * hb.w;
            acc[1].x += pa.y * hb.x; acc[1].y += pa.y * hb.y; acc[1].z += pa.y * hb.z; acc[1].w += pa.y * hb.w;
            acc[2].x += pa.z * hb.x; acc[2].y += pa.z * hb.y; acc[2].z += pa.z * hb.z; acc[2].w += pa.z * hb.w;
            acc[3].x += pa.w * hb.x; acc[3].y += pa.w * hb.y; acc[3].z += pa.w * hb.z; acc[3].w += pa.w * hb.w;
        }
        __syncthreads();
    }

    // ---- epilogue: atomic accumulate into o[b][c][m] ----
#pragma unroll
    for (int i = 0; i < 4; ++i) {
        const int m = m0 + tm * 4 + i;
        const float* ai = (const float*)&acc[i];
#pragma unroll
        for (int j = 0; j < 4; ++j) {
            const int c = tc * 4 + j;
            atomicAdd(&o[((size_t)b * CC + c) * HW + m], ai[j]);
        }
    }
}

// ---------------------------------------------------------------------------
// Kernel 4: y = gamma * o + x   (flat float4 over 1M elements)
// ---------------------------------------------------------------------------
__global__ __launch_bounds__(256) void k_epi(
    const float* __restrict__ o, const float* __restrict__ x,
    const float* __restrict__ gamma, float* __restrict__ y)
{
    const int i = blockIdx.x * 256 + (int)threadIdx.x;  // float4 index
    const float ga = gamma[0];
    const float4 ov = ((const float4*)o)[i];
    const float4 xv = ((const float4*)x)[i];
    float4 yv;
    yv.x = ga * ov.x + xv.x;
    yv.y = ga * ov.y + xv.y;
    yv.z = ga * ov.z + xv.z;
    yv.w = ga * ov.w + xv.w;
    ((float4*)y)[i] = yv;
}

extern "C" void kernel_launch(void* const* d_in, const int* in_sizes, int n_in,
                              void* d_out, int out_size, void* d_ws, size_t ws_size,
                              hipStream_t stream)
{
    const float* x     = (const float*)d_in[0];
    const float* Wf    = (const float*)d_in[1];
    const float* bf    = (const float*)d_in[2];
    const float* Wg    = (const float*)d_in[3];
    const float* bg    = (const float*)d_in[4];
    const float* Wh    = (const float*)d_in[5];
    const float* bh    = (const float*)d_in[6];
    const float* gamma = (const float*)d_in[7];

    float* ws = (float*)d_ws;
    float* f  = ws + OFF_F;
    float* g  = ws + OFF_G;
    float* h  = ws + OFF_H;
    float* zp = ws + OFF_ZP;
    float* o  = ws + OFF_O;
    float* y  = (float*)d_out;

    k_prep<<<dim3(64, 4), 256, 0, stream>>>(x, Wf, bf, Wg, bg, Wh, bh, f, g, h);
    k_zpart<<<dim3(16, 8, 4), 256, 0, stream>>>(f, g, zp);
    k_scale<<<64, 256, 0, stream>>>(zp, h);
    hipMemsetAsync(o, 0, (size_t)NB * CC * HW * sizeof(float), stream);
    k_attn<<<dim3(2, 4, 64), 256, 0, stream>>>(f, g, h, o);
    k_epi<<<1024, 256, 0, stream>>>(o, x, gamma, y);
}

// Round 2
// 174.484 us; speedup vs baseline: 1.5933x; 1.5933x over previous
//
#include <hip/hip_runtime.h>
#include <hip/hip_bf16.h>

#define HW 4096
#define CC 64
#define NB 4

typedef short bf16x8 __attribute__((ext_vector_type(8)));
typedef float f32x4 __attribute__((ext_vector_type(4)));

// workspace layout (byte offsets)
#define OFF_F  0                      // bf16 [b][n][8]     262144 B
#define OFF_G  262144                 // bf16 [b][n][8]     262144 B
#define OFF_H  524288                 // bf16 [b][c][n]    2097152 B
#define OFF_ZP 2621440                // f32  [4ich][b][n]  262144 B
#define OFF_ZI 2883584                // f32  [b][n]         65536 B
#define OFF_O  2949120                // f32  [b][c][m]    4194304 B
// total ~7.14 MB

// ---------------------------------------------------------------------------
// Kernel 1: f/g/h = 1x1 convs, outputs in bf16.
// f,g: [b][n][8] (16B rows = ready-made MFMA fragments). h: [b][c][n]
// (transposed so k_attn can stage B-operand fragments with contiguous 16B).
// ---------------------------------------------------------------------------
__global__ __launch_bounds__(256) void k_prep(
    const float* __restrict__ x,
    const float* __restrict__ Wf, const float* __restrict__ bf,
    const float* __restrict__ Wg, const float* __restrict__ bg,
    const float* __restrict__ Wh, const float* __restrict__ bh,
    __hip_bfloat16* __restrict__ fb, __hip_bfloat16* __restrict__ gb,
    __hip_bfloat16* __restrict__ hb)
{
    const int nt = blockIdx.x, b = blockIdx.y;
    const int tid = (int)threadIdx.x;
    const int w = tid >> 6, nl = tid & 63;
    const int n = nt * 64 + nl;
    const int r0 = w * 20;

    float acc[20];
    const float* wrow[20];
#pragma unroll
    for (int rr = 0; rr < 20; ++rr) {
        int r = r0 + rr;
        if (r < 8)       { wrow[rr] = Wf + r * 64;        acc[rr] = bf[r]; }
        else if (r < 16) { wrow[rr] = Wg + (r - 8) * 64;  acc[rr] = bg[r - 8]; }
        else             { wrow[rr] = Wh + (r - 16) * 64; acc[rr] = bh[r - 16]; }
    }

    const float* xb = x + (size_t)b * CC * HW + n;
    for (int c0 = 0; c0 < 64; c0 += 4) {
        float x0 = xb[(c0 + 0) * HW];
        float x1 = xb[(c0 + 1) * HW];
        float x2 = xb[(c0 + 2) * HW];
        float x3 = xb[(c0 + 3) * HW];
#pragma unroll
        for (int rr = 0; rr < 20; ++rr) {
            const float4 wv = *(const float4*)(wrow[rr] + c0);
            acc[rr] += wv.x * x0 + wv.y * x1 + wv.z * x2 + wv.w * x3;
        }
    }

    const size_t bn = (size_t)b * HW + n;
#pragma unroll
    for (int rr = 0; rr < 20; ++rr) {
        int r = r0 + rr;
        if (r < 8)       fb[bn * 8 + r] = __float2bfloat16(acc[rr]);
        else if (r < 16) gb[bn * 8 + (r - 8)] = __float2bfloat16(acc[rr]);
        else             hb[((size_t)(b * 64 + (r - 16))) * HW + n] = __float2bfloat16(acc[rr]);
    }
}

// ---------------------------------------------------------------------------
// Kernel 2: Z partials via MFMA. Block = (ntile of 64 n) x (i-chunk of 1024).
// Wave w handles i-strips w*16 + it*64; one MFMA per 16x16 s-subtile (K=8
// padded to 32), exp in registers, column-reduce via shfl + LDS.
// ---------------------------------------------------------------------------
__global__ __launch_bounds__(256) void k_z(
    const __hip_bfloat16* __restrict__ fb, const __hip_bfloat16* __restrict__ gb,
    float* __restrict__ zp)
{
    const int nt = blockIdx.x, ich = blockIdx.y, b = blockIdx.z;
    const int n0 = nt * 64;
    const int tid = (int)threadIdx.x;
    const int w = tid >> 6, lane = tid & 63, quad = lane >> 4, l15 = lane & 15;

    __shared__ __align__(16) __hip_bfloat16 gS[64 * 8];
    __shared__ float zred[4][64];

    if (tid < 64)
        *reinterpret_cast<float4*>(&gS[tid * 8]) =
            *reinterpret_cast<const float4*>(gb + ((size_t)b * HW + n0 + tid) * 8);
    __syncthreads();

    const f32x4 cz = {0.f, 0.f, 0.f, 0.f};
    bf16x8 bg[4];
#pragma unroll
    for (int ns = 0; ns < 4; ++ns) {
        bf16x8 v = {0, 0, 0, 0, 0, 0, 0, 0};
        if (quad == 0) v = *reinterpret_cast<const bf16x8*>(&gS[(ns * 16 + l15) * 8]);
        bg[ns] = v;
    }

    float z[4] = {0.f, 0.f, 0.f, 0.f};
    for (int it = 0; it < 16; ++it) {
        const int i = ich * 1024 + it * 64 + w * 16;
        bf16x8 afr = {0, 0, 0, 0, 0, 0, 0, 0};
        if (quad == 0)
            afr = *reinterpret_cast<const bf16x8*>(fb + ((size_t)b * HW + i + l15) * 8);
#pragma unroll
        for (int ns = 0; ns < 4; ++ns) {
            f32x4 s = __builtin_amdgcn_mfma_f32_16x16x32_bf16(afr, bg[ns], cz, 0, 0, 0);
            z[ns] += __expf(s[0]) + __expf(s[1]) + __expf(s[2]) + __expf(s[3]);
        }
    }

#pragma unroll
    for (int ns = 0; ns < 4; ++ns) {
        float v = z[ns];
        v += __shfl_xor(v, 16);
        v += __shfl_xor(v, 32);
        if (quad == 0) zred[w][ns * 16 + l15] = v;
    }
    __syncthreads();
    if (tid < 64) {
        float s = zred[0][tid] + zred[1][tid] + zred[2][tid] + zred[3][tid];
        zp[((size_t)(ich * NB + b)) * HW + n0 + tid] = s;
    }
}

// Kernel 2b: zinv[b][n] = 1 / sum of 4 partials
__global__ __launch_bounds__(256) void k_zred(
    const float* __restrict__ zp, float* __restrict__ zinv)
{
    const int t = blockIdx.x * 256 + (int)threadIdx.x;  // 16384
    const int b = t >> 12, n = t & 4095;
    float s = 0.f;
#pragma unroll
    for (int ic = 0; ic < 4; ++ic) s += zp[((size_t)(ic * NB + b)) * HW + n];
    zinv[(size_t)b * HW + n] = 1.0f / s;
}

// Kernel 2c: h[b][c][n] *= zinv[b][n]  (bf16 in/out)
__global__ __launch_bounds__(256) void k_hscale(
    const float* __restrict__ zinv, __hip_bfloat16* __restrict__ hb)
{
    const int t = blockIdx.x * 256 + (int)threadIdx.x;  // 131072
    const int b = t >> 15;
    const int rc = t & 32767;
    const int c = rc >> 9;
    const int n0 = (rc & 511) << 3;
    __hip_bfloat16* hp = hb + ((size_t)(b * 64 + c)) * HW + n0;
    const float4 z0 = *(const float4*)(zinv + (size_t)b * HW + n0);
    const float4 z1 = *(const float4*)(zinv + (size_t)b * HW + n0 + 4);
    __hip_bfloat16 v[8];
    *(float4*)v = *(const float4*)hp;
    v[0] = __float2bfloat16(__bfloat162float(v[0]) * z0.x);
    v[1] = __float2bfloat16(__bfloat162float(v[1]) * z0.y);
    v[2] = __float2bfloat16(__bfloat162float(v[2]) * z0.z);
    v[3] = __float2bfloat16(__bfloat162float(v[3]) * z0.w);
    v[4] = __float2bfloat16(__bfloat162float(v[4]) * z1.x);
    v[5] = __float2bfloat16(__bfloat162float(v[5]) * z1.y);
    v[6] = __float2bfloat16(__bfloat162float(v[6]) * z1.z);
    v[7] = __float2bfloat16(__bfloat162float(v[7]) * z1.w);
    *(float4*)hp = *(float4*)v;
}

// ---------------------------------------------------------------------------
// Kernel 3: attention. Per chunk: MFMA s-tile (wave w owns 16m strip),
// exp+mask, P->LDS bf16 (stride 72 pad), MFMA P x H (K=64 -> 2 kblk x 4 csub).
// pT rows are wave-private -> no barrier between phase A and B.
// Grid (4 hx, 4 b, 64 r); fold r->mt for load balance; fp32 atomics into o.
// ---------------------------------------------------------------------------
__global__ __launch_bounds__(256) void k_attn(
    const __hip_bfloat16* __restrict__ fb, const __hip_bfloat16* __restrict__ gb,
    const __hip_bfloat16* __restrict__ hb, float* __restrict__ o)
{
    __shared__ __align__(16) __hip_bfloat16 gS[64 * 8];
    __shared__ __align__(16) __hip_bfloat16 hT[64 * 72];
    __shared__ __align__(16) __hip_bfloat16 pT[64 * 72];

    const int hx = blockIdx.x;               // 0..3 n-split
    const int b  = blockIdx.y;
    const int r  = blockIdx.z;
    const int mt = (r < 32) ? r : 95 - r;
    const int m0 = mt * 64;
    const int tid = (int)threadIdx.x;
    const int w = tid >> 6, lane = tid & 63, quad = lane >> 4, l15 = lane & 15;

    const f32x4 cz = {0.f, 0.f, 0.f, 0.f};

    bf16x8 af = {0, 0, 0, 0, 0, 0, 0, 0};
    if (quad == 0)
        af = *reinterpret_cast<const bf16x8*>(fb + ((size_t)b * HW + m0 + w * 16 + l15) * 8);

    f32x4 accO[4];
#pragma unroll
    for (int i = 0; i < 4; ++i) accO[i] = cz;

    for (int nc = mt + hx; nc < 64; nc += 4) {
        const int n0 = nc * 64;
        __syncthreads();   // protect gS/hT from previous phase B readers
        if (tid < 64)
            *reinterpret_cast<float4*>(&gS[tid * 8]) =
                *reinterpret_cast<const float4*>(gb + ((size_t)b * HW + n0 + tid) * 8);
#pragma unroll
        for (int q = 0; q < 2; ++q) {
            const int idx = q * 256 + tid;
            const int c = idx >> 3, ch = idx & 7;
            *reinterpret_cast<float4*>(&hT[c * 72 + ch * 8]) =
                *reinterpret_cast<const float4*>(hb + ((size_t)(b * 64 + c)) * HW + n0 + ch * 8);
        }
        __syncthreads();

        const bool diag = (nc == mt);
        // ---- phase A: s = f.g^T, exp, mask, write P (wave-private rows) ----
#pragma unroll
        for (int ns = 0; ns < 4; ++ns) {
            bf16x8 bg = {0, 0, 0, 0, 0, 0, 0, 0};
            if (quad == 0) bg = *reinterpret_cast<const bf16x8*>(&gS[(ns * 16 + l15) * 8]);
            f32x4 s = __builtin_amdgcn_mfma_f32_16x16x32_bf16(af, bg, cz, 0, 0, 0);
#pragma unroll
            for (int j = 0; j < 4; ++j) {
                float p = __expf(s[j]);
                if (diag) {
                    const int m = m0 + w * 16 + quad * 4 + j;
                    const int n = n0 + ns * 16 + l15;
                    if (n < m) p = 0.f;
                }
                pT[(w * 16 + quad * 4 + j) * 72 + ns * 16 + l15] = __float2bfloat16(p);
            }
        }
        // ---- phase B: accO += P x H ----
#pragma unroll
        for (int kb = 0; kb < 2; ++kb) {
            const bf16x8 ap =
                *reinterpret_cast<const bf16x8*>(&pT[(w * 16 + l15) * 72 + kb * 32 + quad * 8]);
#pragma unroll
            for (int cs = 0; cs < 4; ++cs) {
                const bf16x8 bh =
                    *reinterpret_cast<const bf16x8*>(&hT[(cs * 16 + l15) * 72 + kb * 32 + quad * 8]);
                accO[cs] = __builtin_amdgcn_mfma_f32_16x16x32_bf16(ap, bh, accO[cs], 0, 0, 0);
            }
        }
    }

    // ---- epilogue: atomics into o[b][c][m] ----
#pragma unroll
    for (int cs = 0; cs < 4; ++cs) {
        const int c = cs * 16 + l15;
#pragma unroll
        for (int j = 0; j < 4; ++j) {
            const int m = m0 + w * 16 + quad * 4 + j;
            atomicAdd(o + ((size_t)(b * 64 + c)) * HW + m, accO[cs][j]);
        }
    }
}

// Kernel 4: y = gamma * o + x
__global__ __launch_bounds__(256) void k_epi(
    const float* __restrict__ o, const float* __restrict__ x,
    const float* __restrict__ gamma, float* __restrict__ y)
{
    const int i = blockIdx.x * 256 + (int)threadIdx.x;
    const float ga = gamma[0];
    const float4 ov = ((const float4*)o)[i];
    const float4 xv = ((const float4*)x)[i];
    float4 yv;
    yv.x = ga * ov.x + xv.x;
    yv.y = ga * ov.y + xv.y;
    yv.z = ga * ov.z + xv.z;
    yv.w = ga * ov.w + xv.w;
    ((float4*)y)[i] = yv;
}

extern "C" void kernel_launch(void* const* d_in, const int* in_sizes, int n_in,
                              void* d_out, int out_size, void* d_ws, size_t ws_size,
                              hipStream_t stream)
{
    const float* x     = (const float*)d_in[0];
    const float* Wf    = (const float*)d_in[1];
    const float* bf    = (const float*)d_in[2];
    const float* Wg    = (const float*)d_in[3];
    const float* bg    = (const float*)d_in[4];
    const float* Wh    = (const float*)d_in[5];
    const float* bh    = (const float*)d_in[6];
    const float* gamma = (const float*)d_in[7];

    char* ws = (char*)d_ws;
    __hip_bfloat16* fb = (__hip_bfloat16*)(ws + OFF_F);
    __hip_bfloat16* gb = (__hip_bfloat16*)(ws + OFF_G);
    __hip_bfloat16* hb = (__hip_bfloat16*)(ws + OFF_H);
    float* zp   = (float*)(ws + OFF_ZP);
    float* zinv = (float*)(ws + OFF_ZI);
    float* o    = (float*)(ws + OFF_O);
    float* y    = (float*)d_out;

    k_prep<<<dim3(64, 4), 256, 0, stream>>>(x, Wf, bf, Wg, bg, Wh, bh, fb, gb, hb);
    k_z<<<dim3(64, 4, 4), 256, 0, stream>>>(fb, gb, zp);
    k_zred<<<64, 256, 0, stream>>>(zp, zinv);
    k_hscale<<<512, 256, 0, stream>>>(zinv, hb);
    hipMemsetAsync(o, 0, (size_t)NB * CC * HW * sizeof(float), stream);
    k_attn<<<dim3(4, 4, 64), 256, 0, stream>>>(fb, gb, hb, o);
    k_epi<<<1024, 256, 0, stream>>>(o, x, gamma, y);
}